// Round 7
// baseline (143.025 us; speedup 1.0000x reference)
//
#include <hip/hip_runtime.h>
#include <hip/hip_bf16.h>

typedef __attribute__((ext_vector_type(4))) float f32x4;
typedef __attribute__((ext_vector_type(8))) short bh8;

#define DEVI static __device__ __forceinline__

constexpr int Bn = 2, T = 2048, C = 1024, H = 16, HD = 64;
constexpr int BH = Bn * H;   // 32
constexpr int M  = Bn * T;   // 4096
// fold 1/sqrt(HD) and log2(e) into Q so softmax uses exp2
constexpr float QSC = 0.125f * 1.44269504088896f;

DEVI unsigned short f2bf(float f) {
  unsigned int u = __builtin_bit_cast(unsigned int, f);
  u += 0x7FFFu + ((u >> 16) & 1u);   // RTNE
  return (unsigned short)(u >> 16);
}

DEVI unsigned int cvtpk(float lo, float hi) {  // 2xf32 -> packed 2xbf16 (1 VALU op)
  unsigned int r;
  asm("v_cvt_pk_bf16_f32 %0, %1, %2" : "=v"(r) : "v"(lo), "v"(hi));
  return r;
}

DEVI void gload16(const void* g, void* l) {
  __builtin_amdgcn_global_load_lds((const __attribute__((address_space(1))) void*)g,
                                   (__attribute__((address_space(3))) void*)l,
                                   16, 0, 0);
}

// one fused fp32->bf16 convert for x | w_attn | w_proj (outputs contiguous in ws)
__global__ __launch_bounds__(256) void cvt_all(const float* __restrict__ x,
                                               const float* __restrict__ wa,
                                               const float* __restrict__ wp,
                                               unsigned short* __restrict__ out) {
  constexpr size_t n0 = (size_t)M * C;            // x
  constexpr size_t n1 = n0 + (size_t)3 * C * C;   // + w_attn
  const size_t i = ((size_t)blockIdx.x * 256 + threadIdx.x) * 4;
  const float* src;
  size_t off;
  if (i < n0)      { src = x;  off = i; }
  else if (i < n1) { src = wa; off = i - n0; }
  else             { src = wp; off = i - n1; }
  const float4 v = *(const float4*)(src + off);
  ushort4 o;
  o.x = f2bf(v.x); o.y = f2bf(v.y); o.z = f2bf(v.z); o.w = f2bf(v.w);
  *(ushort4*)(out + i) = o;
}

// ---------------------------------------------------------------------------
// GEMM1: qkv = x @ w_attn^T + b. 256x256 tile, BK=64, 8 waves (2Mx4N),
// 4-phase window with COUNTED vmcnt(8) (T3+T4): tile w+2's halves are staged
// into the buffer being computed, each half right after its last-read barrier;
// loads get 5-7 phases of air time and are drained by vmcnt(8) at the window
// entry (never vmcnt(0) in the loop). Windows 14/15 stage garbage tiles 16/17
// (land inside d_ws, never read) so the vmcnt count stays uniform.
// Epilogue scatters Q (pre-scaled), K, V (transposed + kv-permuted, see attn).
// ---------------------------------------------------------------------------
__global__ __launch_bounds__(512, 2) void gemm256_qkv(
    const unsigned short* __restrict__ A, const unsigned short* __restrict__ Bw,
    const float* __restrict__ bias, int N, int K,
    unsigned short* __restrict__ Qb, unsigned short* __restrict__ Kb,
    unsigned short* __restrict__ Vb) {
  __shared__ unsigned short As[2][256 * 64];
  __shared__ unsigned short Bs[2][256 * 64];

  const int tid  = threadIdx.x;
  const int lane = tid & 63;
  const int wid  = tid >> 6;      // 0..7
  const int wr   = wid >> 2;      // 0..1  M row-group (128 rows)
  const int wc   = wid & 3;       // 0..3  N col-group (64 cols)
  const int m0 = blockIdx.y * 256;
  const int n0 = blockIdx.x * 256;
  const int l15 = lane & 15, l4 = lane >> 4;
  const int sr = lane >> 3;       // staging row-in-slab
  const int sg = lane & 7;        // staging granule

  const unsigned short* Ab = A + (size_t)m0 * K;
  const unsigned short* Bb = Bw + (size_t)n0 * K;

  auto stageA = [&](int buf, int ktile) {
#pragma unroll
    for (int g = 0; g < 4; ++g) {
      const int row = g * 64 + wid * 8 + sr;
      gload16(Ab + (size_t)row * K + ktile + ((sg ^ (row & 7)) * 8),
              &As[buf][(g * 64 + wid * 8) * 64]);
    }
  };
  auto stageB = [&](int buf, int ktile) {
#pragma unroll
    for (int g = 0; g < 4; ++g) {
      const int row = g * 64 + wid * 8 + sr;
      gload16(Bb + (size_t)row * K + ktile + ((sg ^ (row & 7)) * 8),
              &Bs[buf][(g * 64 + wid * 8) * 64]);
    }
  };
  auto ldA = [&](int buf, int i, int kk) -> bh8 {
    const int row  = wr * 128 + i * 16 + l15;
    const int gran = kk * 4 + l4;
    return *(const bh8*)&As[buf][row * 64 + ((gran ^ (row & 7)) * 8)];
  };
  auto ldB = [&](int buf, int j, int kk) -> bh8 {
    const int row  = wc * 64 + j * 16 + l15;
    const int gran = kk * 4 + l4;
    return *(const bh8*)&Bs[buf][row * 64 + ((gran ^ (row & 7)) * 8)];
  };

  f32x4 acc[8][4] = {};

  // prologue: tiles 0 and 1 (8 loads each, in order)
  stageA(0, 0);  stageB(0, 0);
  stageA(1, 64); stageB(1, 64);

  for (int w = 0; w < 16; ++w) {
    const int cb  = w & 1;
    const int kt2 = (w + 2) * 64;

    // window entry: tile-w halves (staged 2 windows ago) drained; newest 8 stay
    asm volatile("s_waitcnt vmcnt(8)" ::: "memory");
    __builtin_amdgcn_s_barrier();
    __builtin_amdgcn_sched_barrier(0);

    bh8 a[4][2], b[4][2];
    // ---- ph0: read A i0-3 + B j0-1; MFMA i0-3 x j0-1 ----
#pragma unroll
    for (int i = 0; i < 4; ++i)
#pragma unroll
      for (int kk = 0; kk < 2; ++kk) a[i][kk] = ldA(cb, i, kk);
#pragma unroll
    for (int j = 0; j < 2; ++j)
#pragma unroll
      for (int kk = 0; kk < 2; ++kk) b[j][kk] = ldB(cb, j, kk);
    __builtin_amdgcn_s_setprio(1);
#pragma unroll
    for (int kk = 0; kk < 2; ++kk)
#pragma unroll
      for (int i = 0; i < 4; ++i)
#pragma unroll
        for (int j = 0; j < 2; ++j)
          acc[i][j] = __builtin_amdgcn_mfma_f32_16x16x32_bf16(a[i][kk], b[j][kk],
                                                              acc[i][j], 0, 0, 0);
    __builtin_amdgcn_s_setprio(0);

    // ---- ph1: read B j2-3; MFMA i0-3 x j2-3 ----
#pragma unroll
    for (int j = 2; j < 4; ++j)
#pragma unroll
      for (int kk = 0; kk < 2; ++kk) b[j][kk] = ldB(cb, j, kk);
    __builtin_amdgcn_s_setprio(1);
#pragma unroll
    for (int kk = 0; kk < 2; ++kk)
#pragma unroll
      for (int i = 0; i < 4; ++i)
#pragma unroll
        for (int j = 2; j < 4; ++j)
          acc[i][j] = __builtin_amdgcn_mfma_f32_16x16x32_bf16(a[i][kk], b[j][kk],
                                                              acc[i][j], 0, 0, 0);
    __builtin_amdgcn_s_setprio(0);
    asm volatile("s_waitcnt lgkmcnt(0)" ::: "memory");
    __builtin_amdgcn_s_barrier();          // B region of cb fully read by all

    // ---- ph2: stage B(w+2) -> cb; read A i4-7; MFMA i4-7 x j2-3 ----
    stageB(cb, kt2);
#pragma unroll
    for (int i = 0; i < 4; ++i)
#pragma unroll
      for (int kk = 0; kk < 2; ++kk) a[i][kk] = ldA(cb, i + 4, kk);
    __builtin_amdgcn_s_setprio(1);
#pragma unroll
    for (int kk = 0; kk < 2; ++kk)
#pragma unroll
      for (int i = 0; i < 4; ++i)
#pragma unroll
        for (int j = 2; j < 4; ++j)
          acc[i + 4][j] = __builtin_amdgcn_mfma_f32_16x16x32_bf16(
              a[i][kk], b[j][kk], acc[i + 4][j], 0, 0, 0);
    __builtin_amdgcn_s_setprio(0);
    asm volatile("s_waitcnt lgkmcnt(0)" ::: "memory");
    __builtin_amdgcn_s_barrier();          // A region of cb fully read by all

    // ---- ph3: stage A(w+2) -> cb; MFMA i4-7 x j0-1 ----
    stageA(cb, kt2);
    __builtin_amdgcn_s_setprio(1);
#pragma unroll
    for (int kk = 0; kk < 2; ++kk)
#pragma unroll
      for (int i = 0; i < 4; ++i)
#pragma unroll
        for (int j = 0; j < 2; ++j)
          acc[i + 4][j] = __builtin_amdgcn_mfma_f32_16x16x32_bf16(
              a[i][kk], b[j][kk], acc[i + 4][j], 0, 0, 0);
    __builtin_amdgcn_s_setprio(0);
  }

  // ---- epilogue: qkv scatter (C/D: col=lane&15, row=(lane>>4)*4+reg) ----
  const int rbase = m0 + wr * 128 + (l4 << 2);
  const int cbase = n0 + wc * 64 + l15;
#pragma unroll
  for (int j = 0; j < 4; ++j) {
    const int n = cbase + j * 16;
    const float bv = bias[n];
    const int part = n >> 10;      // 0:q 1:k 2:v (256-tiles never span parts)
    const int nn = n & 1023;
    const int h = nn >> 6, d = nn & 63;
#pragma unroll
    for (int i = 0; i < 8; ++i)
#pragma unroll
      for (int r = 0; r < 4; ++r) {
        const int m = rbase + i * 16 + r;
        const int b = m >> 11, t = m & (T - 1);
        const int bh = b * H + h;
        const float val = acc[i][j][r] + bv;
        if (part == 0)
          Qb[((size_t)(bh * T + t)) * HD + d] = f2bf(val * QSC);
        else if (part == 1)
          Kb[((size_t)(bh * T + t)) * HD + d] = f2bf(val);
        else {
          // kv-permutation within 128-tile: kp=[kk2|b1|l4|r] -> kap=[kk2|l4|b1|r]
          const int kp  = t & 127;
          const int kap = (kp & ~31) | (((kp >> 2) & 3) << 3) |
                          (((kp >> 4) & 1) << 2) | (kp & 3);
          const int tp  = (t & ~127) | kap;
          Vb[((size_t)(bh * HD + d)) * T + tp] = f2bf(val);  // transposed+permuted
        }
      }
  }
}

// GEMM2: out = y @ w_proj^T + b (fp32). 128x128 tile, BK=64, 4 waves,
// SINGLE-buffered 32KB LDS (R5 structure: occupancy > explicit dbuf, m132).
__global__ __launch_bounds__(256) void gemm128_out(
    const unsigned short* __restrict__ A, const unsigned short* __restrict__ Bw,
    const float* __restrict__ bias, int N, int K, float* __restrict__ Outf) {
  __shared__ unsigned short As[128 * 64];
  __shared__ unsigned short Bs[128 * 64];

  const int tid  = threadIdx.x;
  const int lane = tid & 63;
  const int wid  = tid >> 6;
  const int wm = wid >> 1, wn = wid & 1;
  const int m0 = blockIdx.y * 128;
  const int n0 = blockIdx.x * 128;

  const int srow = lane >> 3;
  const int gp   = lane & 7;

  const unsigned short* Ab = A + (size_t)m0 * K;
  const unsigned short* Bb = Bw + (size_t)n0 * K;

  f32x4 acc[4][4] = {};

  for (int kt = 0; kt < K; kt += 64) {
    __syncthreads();
#pragma unroll
    for (int j = 0; j < 4; ++j) {
      const int row = wid * 32 + j * 8 + srow;
      const int gs  = gp ^ (row & 7);
      gload16(Ab + (size_t)row * K + kt + gs * 8, &As[(wid * 32 + j * 8) * 64]);
    }
#pragma unroll
    for (int j = 0; j < 4; ++j) {
      const int row = wid * 32 + j * 8 + srow;
      const int gs  = gp ^ (row & 7);
      gload16(Bb + (size_t)row * K + kt + gs * 8, &Bs[(wid * 32 + j * 8) * 64]);
    }
    __syncthreads();

#pragma unroll
    for (int kk = 0; kk < 2; ++kk) {
      bh8 af[4], bfr[4];
#pragma unroll
      for (int i = 0; i < 4; ++i) {
        const int row  = wm * 64 + i * 16 + (lane & 15);
        const int gran = kk * 4 + (lane >> 4);
        af[i] = *(const bh8*)&As[row * 64 + ((gran ^ (row & 7)) * 8)];
      }
#pragma unroll
      for (int j = 0; j < 4; ++j) {
        const int row  = wn * 64 + j * 16 + (lane & 15);
        const int gran = kk * 4 + (lane >> 4);
        bfr[j] = *(const bh8*)&Bs[row * 64 + ((gran ^ (row & 7)) * 8)];
      }
#pragma unroll
      for (int i = 0; i < 4; ++i)
#pragma unroll
        for (int j = 0; j < 4; ++j)
          acc[i][j] = __builtin_amdgcn_mfma_f32_16x16x32_bf16(af[i], bfr[j],
                                                              acc[i][j], 0, 0, 0);
    }
  }

  const int rbase = m0 + wm * 64 + ((lane >> 4) << 2);
  const int cbase = n0 + wn * 64 + (lane & 15);
#pragma unroll
  for (int j = 0; j < 4; ++j) {
    const int n = cbase + j * 16;
    const float bv = bias[n];
#pragma unroll
    for (int i = 0; i < 4; ++i)
#pragma unroll
      for (int r = 0; r < 4; ++r) {
        const int m = rbase + i * 16 + r;
        Outf[(size_t)m * N + n] = acc[i][j][r] + bv;
      }
  }
}

// ---------------------------------------------------------------------------
// Flash attention, causal (unchanged from R6). Grid: (BH=32, 8), 512 thr.
// Swapped QK^T + in-register P via cvtpk (kv-permuted V), defer-max,
// 2-phase dbuf prefetch, same-XCD co-location of same-bh blocks.
// ---------------------------------------------------------------------------
__global__ __launch_bounds__(512, 2) void attn(
    const unsigned short* __restrict__ Qb, const unsigned short* __restrict__ Kb,
    const unsigned short* __restrict__ Vb, unsigned short* __restrict__ Yb) {
  __shared__ unsigned short Ks[2][128 * 64];
  __shared__ unsigned short Vs[2][64 * 128];

  const int tid  = threadIdx.x;
  const int lane = tid & 63;
  const int wid  = tid >> 6;          // 0..7
  const int bh   = blockIdx.x;
  const int b = bh >> 4, h = bh & 15;
  const int qa = blockIdx.y;          // 0..7 ; paired tile = 15-qa
  const int na = qa + 1;              // kv-tiles in pass 0

  const int l4  = lane >> 4;          // 0..3
  const int l15 = lane & 15;

  const unsigned short* Kbh = Kb + (size_t)bh * T * HD;
  const unsigned short* Vbh = Vb + (size_t)bh * HD * T;

  const int krow0 = wid * 16;
  const int kr    = lane >> 3;
  const int kgp   = lane & 7;
  const int vrow0 = wid * 8;
  const int vr    = lane >> 4;
  const int vgp   = lane & 15;

  bh8 qk0, qk1;
  {
    const size_t qo = ((size_t)(bh * T + qa * 128 + wid * 16 + l15)) * HD + l4 * 8;
    qk0 = *(const bh8*)&Qb[qo];
    qk1 = *(const bh8*)&Qb[qo + 32];
  }

  f32x4 o[4] = {};
  float mcur = -1e30f, lsum = 0.f;

#pragma unroll
  for (int sl = 0; sl < 2; ++sl) {
    const int row = krow0 + sl * 8 + kr;
    gload16(Kbh + (size_t)row * HD + ((kgp ^ (row & 7)) * 8), &Ks[0][(krow0 + sl * 8) * 64]);
  }
#pragma unroll
  for (int sl = 0; sl < 2; ++sl) {
    const int row = vrow0 + sl * 4 + vr;
    gload16(Vbh + (size_t)row * T + ((vgp ^ (row & 15)) * 8), &Vs[0][(vrow0 + sl * 4) * 128]);
  }
  __syncthreads();

  int cur = 0;
  for (int it = 0; it < 17; ++it) {
    if (it < 16) {
      const int nit = it + 1;
      const int nkt = (nit < na ? nit : nit - na) * 128;
#pragma unroll
      for (int sl = 0; sl < 2; ++sl) {
        const int row = krow0 + sl * 8 + kr;
        gload16(Kbh + (size_t)(nkt + row) * HD + ((kgp ^ (row & 7)) * 8),
                &Ks[cur ^ 1][(krow0 + sl * 8) * 64]);
      }
#pragma unroll
      for (int sl = 0; sl < 2; ++sl) {
        const int row = vrow0 + sl * 4 + vr;
        gload16(Vbh + (size_t)row * T + nkt + ((vgp ^ (row & 15)) * 8),
                &Vs[cur ^ 1][(vrow0 + sl * 4) * 128]);
      }
    }

    if (it == na) {
      const float inv = 1.f / lsum;
      const int t = qa * 128 + wid * 16 + l15;
#pragma unroll
      for (int dj = 0; dj < 4; ++dj) {
        ushort4 hw;
        hw.x = f2bf(o[dj][0] * inv); hw.y = f2bf(o[dj][1] * inv);
        hw.z = f2bf(o[dj][2] * inv); hw.w = f2bf(o[dj][3] * inv);
        *(ushort4*)&Yb[((size_t)(b * T + t)) * C + h * HD + dj * 16 + l4 * 4] = hw;
      }
      mcur = -1e30f; lsum = 0.f;
#pragma unroll
      for (int dj = 0; dj < 4; ++dj) o[dj] = f32x4{0.f, 0.f, 0.f, 0.f};
      const size_t qo = ((size_t)(bh * T + (15 - qa) * 128 + wid * 16 + l15)) * HD + l4 * 8;
      qk0 = *(const bh8*)&Qb[qo];
      qk1 = *(const bh8*)&Qb[qo + 32];
    }

    const int qt   = (it < na) ? qa : 15 - qa;
    const int kt   = (it < na ? it : it - na) * 128;
    const bool diag = (kt == qt * 128);

    f32x4 s[8] = {};
#pragma unroll
    for (int kk = 0; kk < 2; ++kk) {
      bh8 kfr[8];
#pragma unroll
      for (int j = 0; j < 8; ++j) {
        const int row  = j * 16 + l15;
        const int gran = kk * 4 + l4;
        kfr[j] = *(const bh8*)&Ks[cur][row * 64 + ((gran ^ (row & 7)) * 8)];
      }
      const bh8 qf = kk ? qk1 : qk0;
      __builtin_amdgcn_s_setprio(1);
#pragma unroll
      for (int j = 0; j < 8; ++j)
        s[j] = __builtin_amdgcn_mfma_f32_16x16x32_bf16(kfr[j], qf, s[j], 0, 0, 0);
      __builtin_amdgcn_s_setprio(0);
    }

    if (diag) {
      const int qoff = wid * 16 + l15;
#pragma unroll
      for (int j = 0; j < 8; ++j)
#pragma unroll
        for (int r = 0; r < 4; ++r) {
          const int kvoff = j * 16 + l4 * 4 + r;
          if (kvoff > qoff) s[j][r] = -1e30f;
        }
    }

    float mx = fmaxf(fmaxf(s[0][0], s[0][1]), fmaxf(s[0][2], s[0][3]));
#pragma unroll
    for (int j = 1; j < 8; ++j)
      mx = fmaxf(mx, fmaxf(fmaxf(s[j][0], s[j][1]), fmaxf(s[j][2], s[j][3])));
    mx = fmaxf(mx, __shfl_xor(mx, 16));
    mx = fmaxf(mx, __shfl_xor(mx, 32));
    if (__any(mx > mcur + 8.f)) {          // defer-max (T13)
      const float mnew  = fmaxf(mcur, mx);
      const float alpha = exp2f(mcur - mnew);
      mcur = mnew; lsum *= alpha;
#pragma unroll
      for (int dj = 0; dj < 4; ++dj) o[dj] *= alpha;
    }
    float ps = 0.f;
#pragma unroll
    for (int j = 0; j < 8; ++j)
#pragma unroll
      for (int r = 0; r < 4; ++r) {
        const float p = exp2f(s[j][r] - mcur);
        s[j][r] = p;
        ps += p;
      }
    ps += __shfl_xor(ps, 16);
    ps += __shfl_xor(ps, 32);
    lsum += ps;

#pragma unroll
    for (int kk2 = 0; kk2 < 4; ++kk2) {
      const int gran = kk2 * 4 + l4;
      bh8 vf[4];
#pragma unroll
      for (int dj = 0; dj < 4; ++dj) {
        const int row = dj * 16 + l15;
        vf[dj] = *(const bh8*)&Vs[cur][row * 128 + ((gran ^ (row & 15)) * 8)];
      }
      int4 pw;
      pw.x = cvtpk(s[2 * kk2][0], s[2 * kk2][1]);
      pw.y = cvtpk(s[2 * kk2][2], s[2 * kk2][3]);
      pw.z = cvtpk(s[2 * kk2 + 1][0], s[2 * kk2 + 1][1]);
      pw.w = cvtpk(s[2 * kk2 + 1][2], s[2 * kk2 + 1][3]);
      const bh8 pf = __builtin_bit_cast(bh8, pw);
      __builtin_amdgcn_s_setprio(1);
#pragma unroll
      for (int dj = 0; dj < 4; ++dj)
        o[dj] = __builtin_amdgcn_mfma_f32_16x16x32_bf16(vf[dj], pf, o[dj], 0, 0, 0);
      __builtin_amdgcn_s_setprio(0);
    }

    __syncthreads();
    cur ^= 1;
  }

  {
    const float inv = 1.f / lsum;
    const int t = (15 - qa) * 128 + wid * 16 + l15;
#pragma unroll
    for (int dj = 0; dj < 4; ++dj) {
      ushort4 hw;
      hw.x = f2bf(o[dj][0] * inv); hw.y = f2bf(o[dj][1] * inv);
      hw.z = f2bf(o[dj][2] * inv); hw.w = f2bf(o[dj][3] * inv);
      *(ushort4*)&Yb[((size_t)(b * T + t)) * C + h * HD + dj * 16 + l4 * 4] = hw;
    }
  }
}

extern "C" void kernel_launch(void* const* d_in, const int* in_sizes, int n_in,
                              void* d_out, int out_size, void* d_ws, size_t ws_size,
                              hipStream_t stream) {
  const float* x      = (const float*)d_in[0];
  const float* w_attn = (const float*)d_in[1];
  const float* b_attn = (const float*)d_in[2];
  const float* w_proj = (const float*)d_in[3];
  const float* b_proj = (const float*)d_in[4];
  float* out = (float*)d_out;

  unsigned short* xb  = (unsigned short*)d_ws;
  unsigned short* wab = xb  + (size_t)M * C;       // w_attn bf16 [3C][C]
  unsigned short* wpb = wab + (size_t)3 * C * C;   // w_proj bf16 [C][C]
  unsigned short* Qb  = wpb + (size_t)C * C;       // [BH][T][HD] (pre-scaled)
  unsigned short* Kb  = Qb  + (size_t)M * C;       // [BH][T][HD]
  unsigned short* Vb  = Kb  + (size_t)M * C;       // [BH][HD][T] transposed+permuted
  unsigned short* Yb  = xb;                        // alias: xb dead after GEMM1

  constexpr int CVT_BLOCKS = (M * C + 3 * C * C + C * C) / 1024;  // 8192
  cvt_all<<<dim3(CVT_BLOCKS), 256, 0, stream>>>(x, w_attn, w_proj, xb);

  gemm256_qkv<<<dim3(3 * C / 256, M / 256), 512, 0, stream>>>(
      xb, wab, b_attn, 3 * C, C, Qb, Kb, Vb);

  attn<<<dim3(BH, 8), 512, 0, stream>>>(Qb, Kb, Vb, Yb);

  gemm128_out<<<dim3(C / 128, M / 128), 256, 0, stream>>>(
      Yb, wpb, b_proj, C, C, out);
}

// Round 8
// 134.576 us; speedup vs baseline: 1.0628x; 1.0628x over previous
//
#include <hip/hip_runtime.h>
#include <hip/hip_bf16.h>

typedef __attribute__((ext_vector_type(4))) float f32x4;
typedef __attribute__((ext_vector_type(8))) short bh8;

#define DEVI static __device__ __forceinline__

constexpr int Bn = 2, T = 2048, C = 1024, H = 16, HD = 64;
constexpr int BH = Bn * H;   // 32
constexpr int M  = Bn * T;   // 4096
// fold 1/sqrt(HD) and log2(e) into Q so softmax uses exp2
constexpr float QSC = 0.125f * 1.44269504088896f;

DEVI unsigned short f2bf(float f) {
  unsigned int u = __builtin_bit_cast(unsigned int, f);
  u += 0x7FFFu + ((u >> 16) & 1u);   // RTNE
  return (unsigned short)(u >> 16);
}

DEVI unsigned int cvtpk(float lo, float hi) {  // 2xf32 -> packed 2xbf16 (1 VALU op)
  unsigned int r;
  asm("v_cvt_pk_bf16_f32 %0, %1, %2" : "=v"(r) : "v"(lo), "v"(hi));
  return r;
}

DEVI void gload16(const void* g, void* l) {
  __builtin_amdgcn_global_load_lds((const __attribute__((address_space(1))) void*)g,
                                   (__attribute__((address_space(3))) void*)l,
                                   16, 0, 0);
}

// one fused fp32->bf16 convert for x | w_attn | w_proj (outputs contiguous in ws)
__global__ __launch_bounds__(256) void cvt_all(const float* __restrict__ x,
                                               const float* __restrict__ wa,
                                               const float* __restrict__ wp,
                                               unsigned short* __restrict__ out) {
  constexpr size_t n0 = (size_t)M * C;            // x
  constexpr size_t n1 = n0 + (size_t)3 * C * C;   // + w_attn
  const size_t i = ((size_t)blockIdx.x * 256 + threadIdx.x) * 4;
  const float* src;
  size_t off;
  if (i < n0)      { src = x;  off = i; }
  else if (i < n1) { src = wa; off = i - n0; }
  else             { src = wp; off = i - n1; }
  const float4 v = *(const float4*)(src + off);
  ushort4 o;
  o.x = f2bf(v.x); o.y = f2bf(v.y); o.z = f2bf(v.z); o.w = f2bf(v.w);
  *(ushort4*)(out + i) = o;
}

// C = A @ B^T (+bias). 128x128 tile, BK=64, 4 waves, 16x16x32 bf16 MFMA.
// R8: back to the R5 SINGLE-BUFFERED structure (proven fastest: 32KB LDS ->
// 4-5 blocks/CU, implicit cross-block overlap beats explicit pipelining at
// this problem size; both dbuf attempts regressed - m132/m114).
// EPI 0: fp32 out + bias. EPI 1: qkv scatter; V kv-PERMUTED (see attn).
template <int EPI>
__global__ __launch_bounds__(256) void gemm_bt(
    const unsigned short* __restrict__ A, const unsigned short* __restrict__ Bw,
    const float* __restrict__ bias, int N, int K,
    unsigned short* __restrict__ Qb, unsigned short* __restrict__ Kb,
    unsigned short* __restrict__ Vb, float* __restrict__ Outf) {
  __shared__ unsigned short As[128 * 64];
  __shared__ unsigned short Bs[128 * 64];

  const int tid  = threadIdx.x;
  const int lane = tid & 63;
  const int wid  = tid >> 6;
  const int wm = wid >> 1, wn = wid & 1;
  const int m0 = blockIdx.y * 128;
  const int n0 = blockIdx.x * 128;

  const int srow = lane >> 3;
  const int gp   = lane & 7;

  const unsigned short* Ab = A + (size_t)m0 * K;
  const unsigned short* Bb = Bw + (size_t)n0 * K;

  f32x4 acc[4][4] = {};

  for (int kt = 0; kt < K; kt += 64) {
    __syncthreads();
#pragma unroll
    for (int j = 0; j < 4; ++j) {
      const int row = wid * 32 + j * 8 + srow;
      const int gs  = gp ^ (row & 7);
      gload16(Ab + (size_t)row * K + kt + gs * 8, &As[(wid * 32 + j * 8) * 64]);
    }
#pragma unroll
    for (int j = 0; j < 4; ++j) {
      const int row = wid * 32 + j * 8 + srow;
      const int gs  = gp ^ (row & 7);
      gload16(Bb + (size_t)row * K + kt + gs * 8, &Bs[(wid * 32 + j * 8) * 64]);
    }
    __syncthreads();

#pragma unroll
    for (int kk = 0; kk < 2; ++kk) {
      bh8 af[4], bfr[4];
#pragma unroll
      for (int i = 0; i < 4; ++i) {
        const int row  = wm * 64 + i * 16 + (lane & 15);
        const int gran = kk * 4 + (lane >> 4);
        af[i] = *(const bh8*)&As[row * 64 + ((gran ^ (row & 7)) * 8)];
      }
#pragma unroll
      for (int j = 0; j < 4; ++j) {
        const int row  = wn * 64 + j * 16 + (lane & 15);
        const int gran = kk * 4 + (lane >> 4);
        bfr[j] = *(const bh8*)&Bs[row * 64 + ((gran ^ (row & 7)) * 8)];
      }
#pragma unroll
      for (int i = 0; i < 4; ++i)
#pragma unroll
        for (int j = 0; j < 4; ++j)
          acc[i][j] = __builtin_amdgcn_mfma_f32_16x16x32_bf16(af[i], bfr[j],
                                                              acc[i][j], 0, 0, 0);
    }
  }

  const int rbase = m0 + wm * 64 + ((lane >> 4) << 2);
  const int cbase = n0 + wn * 64 + (lane & 15);

  if (EPI == 0) {
#pragma unroll
    for (int j = 0; j < 4; ++j) {
      const int n = cbase + j * 16;
      const float bv = bias[n];
#pragma unroll
      for (int i = 0; i < 4; ++i)
#pragma unroll
        for (int r = 0; r < 4; ++r) {
          const int m = rbase + i * 16 + r;
          Outf[(size_t)m * N + n] = acc[i][j][r] + bv;
        }
    }
  } else {
#pragma unroll
    for (int j = 0; j < 4; ++j) {
      const int n = cbase + j * 16;
      const float bv = bias[n];
      const int part = n >> 10;      // 0:q 1:k 2:v
      const int nn = n & 1023;
      const int h = nn >> 6, d = nn & 63;
#pragma unroll
      for (int i = 0; i < 4; ++i)
#pragma unroll
        for (int r = 0; r < 4; ++r) {
          const int m = rbase + i * 16 + r;
          const int b = m >> 11, t = m & (T - 1);
          const int bh = b * H + h;
          const float val = acc[i][j][r] + bv;
          if (part == 0)
            Qb[((size_t)(bh * T + t)) * HD + d] = f2bf(val * QSC);
          else if (part == 1)
            Kb[((size_t)(bh * T + t)) * HD + d] = f2bf(val);
          else {
            // kv-permutation within 128-tile: kp=[kk2|b1|l4|r] -> kap=[kk2|l4|b1|r]
            const int kp  = t & 127;
            const int kap = (kp & ~31) | (((kp >> 2) & 3) << 3) |
                            (((kp >> 4) & 1) << 2) | (kp & 3);
            const int tp  = (t & ~127) | kap;
            Vb[((size_t)(bh * HD + d)) * T + tp] = f2bf(val);  // transposed+permuted
          }
        }
    }
  }
}

// ---------------------------------------------------------------------------
// Flash attention, causal. Grid: (BH=32, 8). Block: 256 thr = 4 waves.
// R8: 32 q-rows PER WAVE (2 chunks of 16): every K/V fragment ds_read now
// feeds TWO MFMAs, halving per-block LDS traffic (the R5 bottleneck: 256
// b128-reads/iter -> 128). Same pairing (qa, 15-qa; 17 uniform kv-iters),
// same swapped QK^T + in-register P (cvtpk, kv-permuted V), defer-max,
// 2-phase dbuf prefetch, same-XCD co-location of same-bh blocks.
// ---------------------------------------------------------------------------
__global__ __launch_bounds__(256, 2) void attn(
    const unsigned short* __restrict__ Qb, const unsigned short* __restrict__ Kb,
    const unsigned short* __restrict__ Vb, unsigned short* __restrict__ Yb) {
  __shared__ unsigned short Ks[2][128 * 64];
  __shared__ unsigned short Vs[2][64 * 128];

  const int tid  = threadIdx.x;
  const int lane = tid & 63;
  const int wid  = tid >> 6;          // 0..3
  const int bh   = blockIdx.x;
  const int b = bh >> 4, h = bh & 15;
  const int qa = blockIdx.y;          // 0..7 ; paired tile = 15-qa
  const int na = qa + 1;              // kv-tiles in pass 0

  const int l4  = lane >> 4;          // 0..3
  const int l15 = lane & 15;

  const unsigned short* Kbh = Kb + (size_t)bh * T * HD;
  const unsigned short* Vbh = Vb + (size_t)bh * HD * T;

  // staging geometry: wave stages K rows [wid*32, wid*32+32) in 4 slabs of 8,
  // V rows [wid*16, wid*16+16) in 4 slabs of 4 (256B rows).
  const int kr  = lane >> 3, kgp = lane & 7;
  const int vr  = lane >> 4, vgp = lane & 15;

  // Q fragments (B-operand), 2 chunks x 2 kk: Q[q=qbase+c*16+l15][kk*32+l4*8..]
  bh8 qk[2][2];
#pragma unroll
  for (int c = 0; c < 2; ++c) {
    const size_t qo = ((size_t)(bh * T + qa * 128 + wid * 32 + c * 16 + l15)) * HD + l4 * 8;
    qk[c][0] = *(const bh8*)&Qb[qo];
    qk[c][1] = *(const bh8*)&Qb[qo + 32];
  }

  f32x4 o[2][4] = {};
  float mcur[2] = {-1e30f, -1e30f}, lsum[2] = {0.f, 0.f};

  // prologue: stage tile 0 into buffer 0
#pragma unroll
  for (int sl = 0; sl < 4; ++sl) {
    const int row = wid * 32 + sl * 8 + kr;
    gload16(Kbh + (size_t)row * HD + ((kgp ^ (row & 7)) * 8),
            &Ks[0][(wid * 32 + sl * 8) * 64]);
  }
#pragma unroll
  for (int sl = 0; sl < 4; ++sl) {
    const int row = wid * 16 + sl * 4 + vr;
    gload16(Vbh + (size_t)row * T + ((vgp ^ (row & 15)) * 8),
            &Vs[0][(wid * 16 + sl * 4) * 128]);
  }
  __syncthreads();

  int cur = 0;
  for (int it = 0; it < 17; ++it) {
    // ---- prefetch next tile into the other buffer ----
    if (it < 16) {
      const int nit = it + 1;
      const int nkt = (nit < na ? nit : nit - na) * 128;
#pragma unroll
      for (int sl = 0; sl < 4; ++sl) {
        const int row = wid * 32 + sl * 8 + kr;
        gload16(Kbh + (size_t)(nkt + row) * HD + ((kgp ^ (row & 7)) * 8),
                &Ks[cur ^ 1][(wid * 32 + sl * 8) * 64]);
      }
#pragma unroll
      for (int sl = 0; sl < 4; ++sl) {
        const int row = wid * 16 + sl * 4 + vr;
        gload16(Vbh + (size_t)row * T + nkt + ((vgp ^ (row & 15)) * 8),
                &Vs[cur ^ 1][(wid * 16 + sl * 4) * 128]);
      }
    }

    // ---- pass boundary: flush pass-0 output, reinit state ----
    if (it == na) {
#pragma unroll
      for (int c = 0; c < 2; ++c) {
        const float inv = 1.f / lsum[c];
        const int t = qa * 128 + wid * 32 + c * 16 + l15;
#pragma unroll
        for (int dj = 0; dj < 4; ++dj) {
          ushort4 hw;
          hw.x = f2bf(o[c][dj][0] * inv); hw.y = f2bf(o[c][dj][1] * inv);
          hw.z = f2bf(o[c][dj][2] * inv); hw.w = f2bf(o[c][dj][3] * inv);
          *(ushort4*)&Yb[((size_t)(b * T + t)) * C + h * HD + dj * 16 + l4 * 4] = hw;
        }
        mcur[c] = -1e30f; lsum[c] = 0.f;
#pragma unroll
        for (int dj = 0; dj < 4; ++dj) o[c][dj] = f32x4{0.f, 0.f, 0.f, 0.f};
        const size_t qo =
            ((size_t)(bh * T + (15 - qa) * 128 + wid * 32 + c * 16 + l15)) * HD + l4 * 8;
        qk[c][0] = *(const bh8*)&Qb[qo];
        qk[c][1] = *(const bh8*)&Qb[qo + 32];
      }
    }

    const int qt   = (it < na) ? qa : 15 - qa;
    const int kt   = (it < na ? it : it - na) * 128;
    const bool diag = (kt == qt * 128);

    // ---- S^T = K Q^T : s[c][j][r] = S[kv=kt+j*16+l4*4+r][q=..+c*16+l15] ----
    f32x4 s[2][8] = {};
#pragma unroll
    for (int kk = 0; kk < 2; ++kk) {
      __builtin_amdgcn_s_setprio(1);
#pragma unroll
      for (int j = 0; j < 8; ++j) {
        const int row  = j * 16 + l15;
        const int gran = kk * 4 + l4;
        const bh8 kfr = *(const bh8*)&Ks[cur][row * 64 + ((gran ^ (row & 7)) * 8)];
        s[0][j] = __builtin_amdgcn_mfma_f32_16x16x32_bf16(kfr, qk[0][kk], s[0][j], 0, 0, 0);
        s[1][j] = __builtin_amdgcn_mfma_f32_16x16x32_bf16(kfr, qk[1][kk], s[1][j], 0, 0, 0);
      }
      __builtin_amdgcn_s_setprio(0);
    }

    // ---- causal mask (diagonal tile only) ----
    if (diag) {
#pragma unroll
      for (int c = 0; c < 2; ++c) {
        const int qoff = wid * 32 + c * 16 + l15;
#pragma unroll
        for (int j = 0; j < 8; ++j)
#pragma unroll
          for (int r = 0; r < 4; ++r) {
            const int kvoff = j * 16 + l4 * 4 + r;
            if (kvoff > qoff) s[c][j][r] = -1e30f;
          }
      }
    }

    // ---- online softmax: per-lane rows (one per chunk), 2 shuffles each ----
    float mx[2];
#pragma unroll
    for (int c = 0; c < 2; ++c) {
      float m = fmaxf(fmaxf(s[c][0][0], s[c][0][1]), fmaxf(s[c][0][2], s[c][0][3]));
#pragma unroll
      for (int j = 1; j < 8; ++j)
        m = fmaxf(m, fmaxf(fmaxf(s[c][j][0], s[c][j][1]), fmaxf(s[c][j][2], s[c][j][3])));
      m = fmaxf(m, __shfl_xor(m, 16));
      m = fmaxf(m, __shfl_xor(m, 32));
      mx[c] = m;
    }
    const bool grow = (mx[0] > mcur[0] + 8.f) || (mx[1] > mcur[1] + 8.f);
    if (__any(grow)) {                     // defer-max (T13)
#pragma unroll
      for (int c = 0; c < 2; ++c) {
        const float mnew  = fmaxf(mcur[c], mx[c]);
        const float alpha = exp2f(mcur[c] - mnew);
        mcur[c] = mnew; lsum[c] *= alpha;
#pragma unroll
        for (int dj = 0; dj < 4; ++dj) o[c][dj] *= alpha;
      }
    }
#pragma unroll
    for (int c = 0; c < 2; ++c) {
      float ps = 0.f;
#pragma unroll
      for (int j = 0; j < 8; ++j)
#pragma unroll
        for (int r = 0; r < 4; ++r) {
          const float p = exp2f(s[c][j][r] - mcur[c]);
          s[c][j][r] = p;
          ps += p;
        }
      ps += __shfl_xor(ps, 16);
      ps += __shfl_xor(ps, 32);
      lsum[c] += ps;
    }

    // ---- O^T += V^T P : P packed in-register (V kv-permuted at GEMM1) ----
#pragma unroll
    for (int kk2 = 0; kk2 < 4; ++kk2) {
      const int gran = kk2 * 4 + l4;
      int4 pw0, pw1;
      pw0.x = cvtpk(s[0][2 * kk2][0], s[0][2 * kk2][1]);
      pw0.y = cvtpk(s[0][2 * kk2][2], s[0][2 * kk2][3]);
      pw0.z = cvtpk(s[0][2 * kk2 + 1][0], s[0][2 * kk2 + 1][1]);
      pw0.w = cvtpk(s[0][2 * kk2 + 1][2], s[0][2 * kk2 + 1][3]);
      pw1.x = cvtpk(s[1][2 * kk2][0], s[1][2 * kk2][1]);
      pw1.y = cvtpk(s[1][2 * kk2][2], s[1][2 * kk2][3]);
      pw1.z = cvtpk(s[1][2 * kk2 + 1][0], s[1][2 * kk2 + 1][1]);
      pw1.w = cvtpk(s[1][2 * kk2 + 1][2], s[1][2 * kk2 + 1][3]);
      const bh8 pf0 = __builtin_bit_cast(bh8, pw0);
      const bh8 pf1 = __builtin_bit_cast(bh8, pw1);
      __builtin_amdgcn_s_setprio(1);
#pragma unroll
      for (int dj = 0; dj < 4; ++dj) {
        const int row = dj * 16 + l15;
        const bh8 vf = *(const bh8*)&Vs[cur][row * 128 + ((gran ^ (row & 15)) * 8)];
        o[0][dj] = __builtin_amdgcn_mfma_f32_16x16x32_bf16(vf, pf0, o[0][dj], 0, 0, 0);
        o[1][dj] = __builtin_amdgcn_mfma_f32_16x16x32_bf16(vf, pf1, o[1][dj], 0, 0, 0);
      }
      __builtin_amdgcn_s_setprio(0);
    }

    __syncthreads();   // drains vmcnt(0): prefetched tile ready; buffer reuse safe
    cur ^= 1;
  }

  // ---- flush pass-1 output ----
#pragma unroll
  for (int c = 0; c < 2; ++c) {
    const float inv = 1.f / lsum[c];
    const int t = (15 - qa) * 128 + wid * 32 + c * 16 + l15;
#pragma unroll
    for (int dj = 0; dj < 4; ++dj) {
      ushort4 hw;
      hw.x = f2bf(o[c][dj][0] * inv); hw.y = f2bf(o[c][dj][1] * inv);
      hw.z = f2bf(o[c][dj][2] * inv); hw.w = f2bf(o[c][dj][3] * inv);
      *(ushort4*)&Yb[((size_t)(b * T + t)) * C + h * HD + dj * 16 + l4 * 4] = hw;
    }
  }
}

extern "C" void kernel_launch(void* const* d_in, const int* in_sizes, int n_in,
                              void* d_out, int out_size, void* d_ws, size_t ws_size,
                              hipStream_t stream) {
  const float* x      = (const float*)d_in[0];
  const float* w_attn = (const float*)d_in[1];
  const float* b_attn = (const float*)d_in[2];
  const float* w_proj = (const float*)d_in[3];
  const float* b_proj = (const float*)d_in[4];
  float* out = (float*)d_out;

  unsigned short* xb  = (unsigned short*)d_ws;
  unsigned short* wab = xb  + (size_t)M * C;       // w_attn bf16 [3C][C]
  unsigned short* wpb = wab + (size_t)3 * C * C;   // w_proj bf16 [C][C]
  unsigned short* Qb  = wpb + (size_t)C * C;       // [BH][T][HD] (pre-scaled)
  unsigned short* Kb  = Qb  + (size_t)M * C;       // [BH][T][HD]
  unsigned short* Vb  = Kb  + (size_t)M * C;       // [BH][HD][T] transposed+permuted
  unsigned short* Yb  = xb;                        // alias: xb dead after GEMM1

  constexpr int CVT_BLOCKS = (M * C + 3 * C * C + C * C) / 1024;  // 8192
  cvt_all<<<dim3(CVT_BLOCKS), 256, 0, stream>>>(x, w_attn, w_proj, xb);

  gemm_bt<1><<<dim3(3 * C / 128, M / 128), 256, 0, stream>>>(
      xb, wab, b_attn, 3 * C, C, Qb, Kb, Vb, nullptr);

  attn<<<dim3(BH, 8), 256, 0, stream>>>(Qb, Kb, Vb, Yb);

  gemm_bt<0><<<dim3(C / 128, M / 128), 256, 0, stream>>>(
      Yb, wpb, b_proj, C, C, nullptr, nullptr, nullptr, out);
}